// Round 1
// baseline (341.202 us; speedup 1.0000x reference)
//
#include <hip/hip_runtime.h>
#include <cstdint>
#include <cstddef>

// MultiHeadAttention: B=2,S=2048,D_MODEL=1024,N_HEAD=16, "buggy" reshape:
// head h of batch b is the contiguous block X[b, h*128:(h+1)*128, :] viewed (2048,64).
// Pipeline: cast->f16, W transpose-cast, QKV proj GEMM (mfma f16), flash attn, out GEMM.
// All compute fp16 inputs / fp32 accumulate (threshold 7.97e-2 is bf16-floor; fp16 is 8x tighter).

typedef _Float16 f16;
typedef _Float16 f16x8 __attribute__((ext_vector_type(8)));
typedef float f32x4 __attribute__((ext_vector_type(4)));

#define NB 2
#define NS 2048
#define NDM 1024
#define NHEAD 16
#define NHD 64

// ---------------- cast fp32 -> fp16 (q,k,v), 8 elems/thread ----------------
__global__ __launch_bounds__(256) void cast3_kernel(
    const float* __restrict__ s0, const float* __restrict__ s1, const float* __restrict__ s2,
    f16* __restrict__ d0, f16* __restrict__ d1, f16* __restrict__ d2, int nvec)
{
    const float* s = blockIdx.z == 0 ? s0 : (blockIdx.z == 1 ? s1 : s2);
    f16* d        = blockIdx.z == 0 ? d0 : (blockIdx.z == 1 ? d1 : d2);
    int vi = blockIdx.x * 256 + threadIdx.x;
    if (vi >= nvec) return;
    const float4* sp = (const float4*)s;
    float4 a = sp[vi * 2 + 0];
    float4 b = sp[vi * 2 + 1];
    f16x8 h;
    h[0] = (f16)a.x; h[1] = (f16)a.y; h[2] = (f16)a.z; h[3] = (f16)a.w;
    h[4] = (f16)b.x; h[5] = (f16)b.y; h[6] = (f16)b.z; h[7] = (f16)b.w;
    *(f16x8*)(d + (size_t)vi * 8) = h;
}

// ---------------- transpose + cast the 1024x1024 weight mats ----------------
// T[n][k] = (f16)W[k][n]  so GEMMs read both operands K-contiguous.
__global__ __launch_bounds__(256) void tcast4_kernel(
    const float* __restrict__ w0, const float* __restrict__ w1,
    const float* __restrict__ w2, const float* __restrict__ w3,
    f16* __restrict__ t0, f16* __restrict__ t1, f16* __restrict__ t2, f16* __restrict__ t3)
{
    const int n = 1024;
    const float* W; f16* T;
    switch (blockIdx.z) {
        case 0: W = w0; T = t0; break;
        case 1: W = w1; T = t1; break;
        case 2: W = w2; T = t2; break;
        default: W = w3; T = t3; break;
    }
    __shared__ float tile[32][33];
    int tx = threadIdx.x, ty = threadIdx.y;     // block (32,8)
    int c0 = blockIdx.x * 32, r0 = blockIdx.y * 32;
    #pragma unroll
    for (int i = 0; i < 32; i += 8)
        tile[ty + i][tx] = W[(size_t)(r0 + ty + i) * n + c0 + tx];
    __syncthreads();
    #pragma unroll
    for (int i = 0; i < 32; i += 8)
        T[(size_t)(c0 + ty + i) * n + r0 + tx] = (f16)tile[tx][ty + i];
}

// ---------------- GEMM  C(MxN) = A(MxK) * Bt(NxK)^T, 128x128 tile, BK=64 ----------------
// 4 waves in 2x2; each wave 64x64 via 4x4 frags of mfma_f32_16x16x32_f16.
// A-frag: m=lane&15, k=quad*8+j ; B-frag: n=lane&15, k=quad*8+j ; C: row=quad*4+r, col=lane&15.
template <typename CT>
__device__ __forceinline__ void gemm_abt_body(
    const f16* __restrict__ A, const f16* __restrict__ Bt, CT* __restrict__ C,
    int M, int N, int K, int bx, int by)
{
    __shared__ f16 As[128][72];   // +8 pad: 2-way banks on b128 frag reads
    __shared__ f16 Bs[128][72];
    const int tid  = threadIdx.x;
    const int lane = tid & 63, wave = tid >> 6;
    const int quad = lane >> 4, ln = lane & 15;
    const int wm = wave >> 1, wn = wave & 1;
    const int m0 = by * 128, n0 = bx * 128;

    f32x4 acc[4][4] = {};
    for (int k0 = 0; k0 < K; k0 += 64) {
        __syncthreads();
        #pragma unroll
        for (int i = 0; i < 4; i++) {
            int vi = tid + i * 256;                 // 0..1023
            int row = vi >> 3, kk = (vi & 7) * 8;
            *(uint4*)&As[row][kk] = *(const uint4*)&A [(size_t)(m0 + row) * K + k0 + kk];
            *(uint4*)&Bs[row][kk] = *(const uint4*)&Bt[(size_t)(n0 + row) * K + k0 + kk];
        }
        __syncthreads();
        #pragma unroll
        for (int kc = 0; kc < 2; kc++) {
            f16x8 af[4], bfr[4];
            #pragma unroll
            for (int mt = 0; mt < 4; mt++)
                af[mt] = *(const f16x8*)&As[wm * 64 + mt * 16 + ln][kc * 32 + quad * 8];
            #pragma unroll
            for (int nt = 0; nt < 4; nt++)
                bfr[nt] = *(const f16x8*)&Bs[wn * 64 + nt * 16 + ln][kc * 32 + quad * 8];
            #pragma unroll
            for (int mt = 0; mt < 4; mt++)
                #pragma unroll
                for (int nt = 0; nt < 4; nt++)
                    acc[mt][nt] = __builtin_amdgcn_mfma_f32_16x16x32_f16(af[mt], bfr[nt], acc[mt][nt], 0, 0, 0);
        }
    }
    #pragma unroll
    for (int mt = 0; mt < 4; mt++)
        #pragma unroll
        for (int nt = 0; nt < 4; nt++)
            #pragma unroll
            for (int r = 0; r < 4; r++) {
                int row = m0 + wm * 64 + mt * 16 + quad * 4 + r;
                int col = n0 + wn * 64 + nt * 16 + ln;
                C[(size_t)row * N + col] = (CT)acc[mt][nt][r];
            }
}

__global__ __launch_bounds__(256) void gemm3_kernel(
    const f16* __restrict__ a0, const f16* __restrict__ a1, const f16* __restrict__ a2,
    const f16* __restrict__ b0, const f16* __restrict__ b1, const f16* __restrict__ b2,
    f16* __restrict__ c0, f16* __restrict__ c1, f16* __restrict__ c2, int M, int N, int K)
{
    const f16 *A, *Bt; f16* C;
    switch (blockIdx.z) {
        case 0: A = a0; Bt = b0; C = c0; break;
        case 1: A = a1; Bt = b1; C = c1; break;
        default: A = a2; Bt = b2; C = c2; break;
    }
    gemm_abt_body<f16>(A, Bt, C, M, N, K, blockIdx.x, blockIdx.y);
}

__global__ __launch_bounds__(256) void gemm_out_kernel(
    const f16* __restrict__ A, const f16* __restrict__ Bt, float* __restrict__ C, int M, int N, int K)
{
    gemm_abt_body<float>(A, Bt, C, M, N, K, blockIdx.x, blockIdx.y);
}

// ---------------- flash attention over the reshaped heads ----------------
// Per block: BQ=64 queries of head (b,h), loop key tiles BK=128, online softmax.
// Wave w owns query rows [w*16, w*16+16). LDS < 64KB -> 2 blocks/CU.
__global__ __launch_bounds__(256) void attn_kernel(
    const f16* __restrict__ Qp, const f16* __restrict__ Kp, const f16* __restrict__ Vp,
    f16* __restrict__ att)
{
    const int qt = blockIdx.x;   // 0..31 (query tile of 64)
    const int h  = blockIdx.y;   // 0..15
    const int b  = blockIdx.z;   // 0..1
    const size_t hb = (size_t)b * (NS * NDM) + (size_t)h * (128 * NDM); // head block base
    const f16* Qh = Qp + hb;     // (2048, 64) row-major, contiguous
    const f16* Kh = Kp + hb;
    const f16* Vh = Vp + hb;

    __shared__ f16 Qs[64][72];      //  9.0 KB
    __shared__ f16 Ks[128][72];     // 18.0 KB
    __shared__ f16 Vt[64][136];     // 17.0 KB  V transposed: Vt[d2][key]
    __shared__ f16 PU[9216];        // 18.0 KB  union: Vtmp[128][72] <-> Ps[64][136]

    const int tid  = threadIdx.x;
    const int lane = tid & 63, wave = tid >> 6;
    const int quad = lane >> 4, ln = lane & 15;

    // stage Q tile (contiguous 64x64)
    #pragma unroll
    for (int i = 0; i < 2; i++) {
        int vi = tid + i * 256;
        int row = vi >> 3, kk = (vi & 7) * 8;
        *(uint4*)&Qs[row][kk] = *(const uint4*)&Qh[(size_t)(qt * 64 + row) * 64 + kk];
    }
    __syncthreads();
    f16x8 qf[2];
    #pragma unroll
    for (int kc = 0; kc < 2; kc++)
        qf[kc] = *(const f16x8*)&Qs[wave * 16 + ln][kc * 32 + quad * 8];

    float m_i[4], l_i[4];
    #pragma unroll
    for (int r = 0; r < 4; r++) { m_i[r] = -3e30f; l_i[r] = 0.f; }
    f32x4 o[4] = {};   // O accumulator: rows=queries (C layout), cols d2 = vt*16+ln

    const int nkt = ((qt * 64 + 63) >> 7) + 1;   // causal: key tiles 0..nkt-1
    for (int kt = 0; kt < nkt; kt++) {
        __syncthreads();   // prev iter readers of Ks/Vt/PU done
        // stage K (128x64) and V (128x64, into PU as Vtmp[128][72])
        #pragma unroll
        for (int i = 0; i < 4; i++) {
            int vi = tid + i * 256;
            int row = vi >> 3, kk = (vi & 7) * 8;
            *(uint4*)&Ks[row][kk]       = *(const uint4*)&Kh[(size_t)(kt * 128 + row) * 64 + kk];
            *(uint4*)&PU[row * 72 + kk] = *(const uint4*)&Vh[(size_t)(kt * 128 + row) * 64 + kk];
        }
        __syncthreads();
        // transpose Vtmp -> Vt
        #pragma unroll
        for (int i = 0; i < 4; i++) {
            int vi = tid + i * 256;
            int row = vi >> 3, kk = (vi & 7) * 8;
            f16x8 vv = *(const f16x8*)&PU[row * 72 + kk];
            #pragma unroll
            for (int j = 0; j < 8; j++) Vt[kk + j][row] = vv[j];
        }
        // S = Q K^T : wave's 16 rows x 128 keys
        f32x4 sf[8] = {};
        #pragma unroll
        for (int kc = 0; kc < 2; kc++) {
            #pragma unroll
            for (int ct = 0; ct < 8; ct++) {
                f16x8 kf = *(const f16x8*)&Ks[ct * 16 + ln][kc * 32 + quad * 8];
                sf[ct] = __builtin_amdgcn_mfma_f32_16x16x32_f16(qf[kc], kf, sf[ct], 0, 0, 0);
            }
        }
        // causal mask (only the last key tile straddles the diagonal)
        if (kt == nkt - 1) {
            #pragma unroll
            for (int ct = 0; ct < 8; ct++) {
                int jg = kt * 128 + ct * 16 + ln;
                #pragma unroll
                for (int r = 0; r < 4; r++) {
                    int ig = qt * 64 + wave * 16 + quad * 4 + r;
                    if (jg > ig) sf[ct][r] = -3e30f;
                }
            }
        }
        // online softmax (row stats across 16 lanes of same quad + 8 in-reg cols)
        float alpha[4];
        #pragma unroll
        for (int r = 0; r < 4; r++) {
            float tm = sf[0][r];
            #pragma unroll
            for (int ct = 1; ct < 8; ct++) tm = fmaxf(tm, sf[ct][r]);
            #pragma unroll
            for (int off = 1; off < 16; off <<= 1) tm = fmaxf(tm, __shfl_xor(tm, off, 64));
            float mnew = fmaxf(m_i[r], tm);
            float a = __expf(m_i[r] - mnew);
            float rs = 0.f;
            #pragma unroll
            for (int ct = 0; ct < 8; ct++) {
                float p = __expf(sf[ct][r] - mnew);
                sf[ct][r] = p; rs += p;
            }
            #pragma unroll
            for (int off = 1; off < 16; off <<= 1) rs += __shfl_xor(rs, off, 64);
            m_i[r] = mnew; l_i[r] = l_i[r] * a + rs; alpha[r] = a;
        }
        #pragma unroll
        for (int vt = 0; vt < 4; vt++)
            #pragma unroll
            for (int r = 0; r < 4; r++) o[vt][r] *= alpha[r];
        __syncthreads();   // all transposes done; PU may be overwritten with P
        // write P (C layout -> Ps[64][136]) for the A-layout round trip
        #pragma unroll
        for (int ct = 0; ct < 8; ct++)
            #pragma unroll
            for (int r = 0; r < 4; r++)
                PU[(wave * 16 + quad * 4 + r) * 136 + ct * 16 + ln] = (f16)sf[ct][r];
        __syncthreads();
        // O += P V
        #pragma unroll
        for (int kc = 0; kc < 4; kc++) {
            f16x8 pa = *(const f16x8*)&PU[(wave * 16 + ln) * 136 + kc * 32 + quad * 8];
            #pragma unroll
            for (int vt = 0; vt < 4; vt++) {
                f16x8 vb = *(const f16x8*)&Vt[vt * 16 + ln][kc * 32 + quad * 8];
                o[vt] = __builtin_amdgcn_mfma_f32_16x16x32_f16(pa, vb, o[vt], 0, 0, 0);
            }
        }
    }
    // epilogue: normalize, scatter to att[(b,s2, h*64+d2)]
    #pragma unroll
    for (int r = 0; r < 4; r++) {
        float inv = 1.0f / l_i[r];
        int s2 = qt * 64 + wave * 16 + quad * 4 + r;
        #pragma unroll
        for (int vt = 0; vt < 4; vt++) {
            int d2 = vt * 16 + ln;
            att[((size_t)b * NS + s2) * NDM + h * 64 + d2] = (f16)(o[vt][r] * inv);
        }
    }
}

extern "C" void kernel_launch(void* const* d_in, const int* in_sizes, int n_in,
                              void* d_out, int out_size, void* d_ws, size_t ws_size,
                              hipStream_t stream)
{
    const float* q  = (const float*)d_in[0];
    const float* k  = (const float*)d_in[1];
    const float* v  = (const float*)d_in[2];
    const float* Wq = (const float*)d_in[3];
    const float* Wk = (const float*)d_in[4];
    const float* Wv = (const float*)d_in[5];
    const float* Wp = (const float*)d_in[6];
    float* out = (float*)d_out;

    // workspace layout (64 MB total)
    char* ws = (char*)d_ws;
    const size_t MB = 1024 * 1024;
    f16* qb   = (f16*)(ws + 0 * MB);    // 8 MB each
    f16* kb   = (f16*)(ws + 8 * MB);
    f16* vb   = (f16*)(ws + 16 * MB);
    f16* Wqt  = (f16*)(ws + 24 * MB);   // 2 MB each (transposed f16 weights)
    f16* Wkt  = (f16*)(ws + 26 * MB);
    f16* Wvt  = (f16*)(ws + 28 * MB);
    f16* Wpt  = (f16*)(ws + 30 * MB);
    f16* Qp   = (f16*)(ws + 32 * MB);   // projections, (4096,1024) f16 row-major
    f16* Kp   = (f16*)(ws + 40 * MB);
    f16* Vp   = (f16*)(ws + 48 * MB);
    f16* attb = (f16*)(ws + 56 * MB);   // attention output (4096,1024) f16

    const int M = NB * NS;      // 4096
    const int N = NDM;          // 1024
    const int K = NDM;          // 1024

    cast3_kernel<<<dim3(2048, 1, 3), 256, 0, stream>>>(q, k, v, qb, kb, vb, (M * NDM) / 8);
    tcast4_kernel<<<dim3(32, 32, 4), dim3(32, 8), 0, stream>>>(Wq, Wk, Wv, Wp, Wqt, Wkt, Wvt, Wpt);
    gemm3_kernel<<<dim3(N / 128, M / 128, 3), 256, 0, stream>>>(qb, kb, vb, Wqt, Wkt, Wvt, Qp, Kp, Vp, M, N, K);
    attn_kernel<<<dim3(NS / 64, NHEAD, NB), 256, 0, stream>>>(Qp, Kp, Vp, attb);
    gemm_out_kernel<<<dim3(N / 128, M / 128, 1), 256, 0, stream>>>(attb, Wpt, out, M, N, K);
}

// Round 2
// 300.969 us; speedup vs baseline: 1.1337x; 1.1337x over previous
//
#include <hip/hip_runtime.h>
#include <cstdint>
#include <cstddef>

// MultiHeadAttention: B=2,S=2048,D_MODEL=1024,N_HEAD=16, "buggy" reshape:
// head h of batch b is the contiguous block X[b, h*128:(h+1)*128, :] viewed (2048,64).
// Pipeline: cast->f16, W transpose-cast, QKV proj GEMM (mfma f16), global V transpose,
// flash attn (BQ=BK=64, 36KB LDS -> 4 blocks/CU, per-wave-private P), out GEMM.

typedef _Float16 f16;
typedef _Float16 f16x8 __attribute__((ext_vector_type(8)));
typedef float f32x4 __attribute__((ext_vector_type(4)));

#define NB 2
#define NS 2048
#define NDM 1024
#define NHEAD 16
#define NHD 64

// ---------------- cast fp32 -> fp16 (q,k,v), 8 elems/thread ----------------
__global__ __launch_bounds__(256) void cast3_kernel(
    const float* __restrict__ s0, const float* __restrict__ s1, const float* __restrict__ s2,
    f16* __restrict__ d0, f16* __restrict__ d1, f16* __restrict__ d2, int nvec)
{
    const float* s = blockIdx.z == 0 ? s0 : (blockIdx.z == 1 ? s1 : s2);
    f16* d        = blockIdx.z == 0 ? d0 : (blockIdx.z == 1 ? d1 : d2);
    int vi = blockIdx.x * 256 + threadIdx.x;
    if (vi >= nvec) return;
    const float4* sp = (const float4*)s;
    float4 a = sp[vi * 2 + 0];
    float4 b = sp[vi * 2 + 1];
    f16x8 h;
    h[0] = (f16)a.x; h[1] = (f16)a.y; h[2] = (f16)a.z; h[3] = (f16)a.w;
    h[4] = (f16)b.x; h[5] = (f16)b.y; h[6] = (f16)b.z; h[7] = (f16)b.w;
    *(f16x8*)(d + (size_t)vi * 8) = h;
}

// ---------------- transpose + cast the 1024x1024 weight mats ----------------
__global__ __launch_bounds__(256) void tcast4_kernel(
    const float* __restrict__ w0, const float* __restrict__ w1,
    const float* __restrict__ w2, const float* __restrict__ w3,
    f16* __restrict__ t0, f16* __restrict__ t1, f16* __restrict__ t2, f16* __restrict__ t3)
{
    const int n = 1024;
    const float* W; f16* T;
    switch (blockIdx.z) {
        case 0: W = w0; T = t0; break;
        case 1: W = w1; T = t1; break;
        case 2: W = w2; T = t2; break;
        default: W = w3; T = t3; break;
    }
    __shared__ float tile[32][33];
    int tx = threadIdx.x, ty = threadIdx.y;     // block (32,8)
    int c0 = blockIdx.x * 32, r0 = blockIdx.y * 32;
    #pragma unroll
    for (int i = 0; i < 32; i += 8)
        tile[ty + i][tx] = W[(size_t)(r0 + ty + i) * n + c0 + tx];
    __syncthreads();
    #pragma unroll
    for (int i = 0; i < 32; i += 8)
        T[(size_t)(c0 + ty + i) * n + r0 + tx] = (f16)tile[tx][ty + i];
}

// ---------------- GEMM  C(MxN) = A(MxK) * Bt(NxK)^T, 128x128 tile, BK=64 ----------------
template <typename CT>
__device__ __forceinline__ void gemm_abt_body(
    const f16* __restrict__ A, const f16* __restrict__ Bt, CT* __restrict__ C,
    int M, int N, int K, int bx, int by)
{
    __shared__ f16 As[128][72];
    __shared__ f16 Bs[128][72];
    const int tid  = threadIdx.x;
    const int lane = tid & 63, wave = tid >> 6;
    const int quad = lane >> 4, ln = lane & 15;
    const int wm = wave >> 1, wn = wave & 1;
    const int m0 = by * 128, n0 = bx * 128;

    f32x4 acc[4][4] = {};
    for (int k0 = 0; k0 < K; k0 += 64) {
        __syncthreads();
        #pragma unroll
        for (int i = 0; i < 4; i++) {
            int vi = tid + i * 256;                 // 0..1023
            int row = vi >> 3, kk = (vi & 7) * 8;
            *(uint4*)&As[row][kk] = *(const uint4*)&A [(size_t)(m0 + row) * K + k0 + kk];
            *(uint4*)&Bs[row][kk] = *(const uint4*)&Bt[(size_t)(n0 + row) * K + k0 + kk];
        }
        __syncthreads();
        #pragma unroll
        for (int kc = 0; kc < 2; kc++) {
            f16x8 af[4], bfr[4];
            #pragma unroll
            for (int mt = 0; mt < 4; mt++)
                af[mt] = *(const f16x8*)&As[wm * 64 + mt * 16 + ln][kc * 32 + quad * 8];
            #pragma unroll
            for (int nt = 0; nt < 4; nt++)
                bfr[nt] = *(const f16x8*)&Bs[wn * 64 + nt * 16 + ln][kc * 32 + quad * 8];
            #pragma unroll
            for (int mt = 0; mt < 4; mt++)
                #pragma unroll
                for (int nt = 0; nt < 4; nt++)
                    acc[mt][nt] = __builtin_amdgcn_mfma_f32_16x16x32_f16(af[mt], bfr[nt], acc[mt][nt], 0, 0, 0);
        }
    }
    #pragma unroll
    for (int mt = 0; mt < 4; mt++)
        #pragma unroll
        for (int nt = 0; nt < 4; nt++)
            #pragma unroll
            for (int r = 0; r < 4; r++) {
                int row = m0 + wm * 64 + mt * 16 + quad * 4 + r;
                int col = n0 + wn * 64 + nt * 16 + ln;
                C[(size_t)row * N + col] = (CT)acc[mt][nt][r];
            }
}

__global__ __launch_bounds__(256) void gemm3_kernel(
    const f16* __restrict__ a0, const f16* __restrict__ a1, const f16* __restrict__ a2,
    const f16* __restrict__ b0, const f16* __restrict__ b1, const f16* __restrict__ b2,
    f16* __restrict__ c0, f16* __restrict__ c1, f16* __restrict__ c2, int M, int N, int K)
{
    const f16 *A, *Bt; f16* C;
    switch (blockIdx.z) {
        case 0: A = a0; Bt = b0; C = c0; break;
        case 1: A = a1; Bt = b1; C = c1; break;
        default: A = a2; Bt = b2; C = c2; break;
    }
    gemm_abt_body<f16>(A, Bt, C, M, N, K, blockIdx.x, blockIdx.y);
}

__global__ __launch_bounds__(256) void gemm_out_kernel(
    const f16* __restrict__ A, const f16* __restrict__ Bt, float* __restrict__ C, int M, int N, int K)
{
    gemm_abt_body<float>(A, Bt, C, M, N, K, blockIdx.x, blockIdx.y);
}

// ---------------- global V transpose: per head (2048x64) -> (64x2048) ----------------
// XOR-swizzle on 8-f16 chunks: element (key,d2) at Ls[key][((d2>>3)^((key>>3)&7))*8 + (d2&7)].
// Both LDS sides conflict-free; both global sides coalesced (8x128B segments per wave).
__global__ __launch_bounds__(256) void vtrans_kernel(
    const f16* __restrict__ Vp, f16* __restrict__ Vt)
{
    const int kt = blockIdx.x;   // key tile of 64
    const int h  = blockIdx.y;
    const int b  = blockIdx.z;
    const f16* src = Vp + (size_t)b * (NS * NDM) + (size_t)h * (128 * NDM);  // (2048,64)
    f16* dst = Vt + (size_t)(b * NHEAD + h) * (64 * 2048);

    __shared__ f16 Ls[64][64];
    const int tid = threadIdx.x;
    #pragma unroll
    for (int i = 0; i < 2; i++) {
        int vi = tid + i * 256;
        int key = vi >> 3, c = vi & 7;
        int cs = c ^ ((key >> 3) & 7);
        *(uint4*)&Ls[key][cs * 8] = *(const uint4*)&src[(size_t)(kt * 64 + key) * 64 + c * 8];
    }
    __syncthreads();
    #pragma unroll
    for (int i = 0; i < 2; i++) {
        int vi = tid + i * 256;
        int d2 = vi >> 3, kc = vi & 7;
        int cs = (d2 >> 3) ^ kc;    // key>>3 == kc for key = kc*8+j
        f16 tmp[8];
        #pragma unroll
        for (int j = 0; j < 8; j++)
            tmp[j] = Ls[kc * 8 + j][cs * 8 + (d2 & 7)];
        *(uint4*)&dst[(size_t)d2 * 2048 + kt * 64 + kc * 8] = *(uint4*)tmp;
    }
}

// ---------------- flash attention v2 ----------------
// BQ=64 (4 waves x 16 q-rows), BK=64, V pre-transposed globally.
// LDS 36KB -> 4 blocks/CU. Per-wave-private P -> no barrier around P round-trip.
__global__ __launch_bounds__(256) void attn_kernel(
    const f16* __restrict__ Qp, const f16* __restrict__ Kp, const f16* __restrict__ Vt,
    f16* __restrict__ att)
{
    const int qt = gridDim.x - 1 - blockIdx.x;  // long (high-qt) blocks dispatch first
    const int h  = blockIdx.y;
    const int b  = blockIdx.z;
    const size_t hb = (size_t)b * (NS * NDM) + (size_t)h * (128 * NDM);
    const f16* Qh = Qp + hb;                                   // (2048,64)
    const f16* Kh = Kp + hb;                                   // (2048,64)
    const f16* Vh = Vt + (size_t)(b * NHEAD + h) * (64 * 2048); // (64,2048) transposed

    __shared__ f16 Qs[64][72];       // 9 KB
    __shared__ f16 Ks[64][72];       // 9 KB
    __shared__ f16 Vs[64][72];       // 9 KB   Vs[d2][key]
    __shared__ f16 Ps[4][16][72];    // 9 KB   per-wave-private P

    const int tid  = threadIdx.x;
    const int lane = tid & 63, wave = tid >> 6;
    const int quad = lane >> 4, ln = lane & 15;

    // stage Q tile once
    #pragma unroll
    for (int i = 0; i < 2; i++) {
        int vi = tid + i * 256;
        int row = vi >> 3, kk = (vi & 7) * 8;
        *(uint4*)&Qs[row][kk] = *(const uint4*)&Qh[(size_t)(qt * 64 + row) * 64 + kk];
    }
    __syncthreads();
    f16x8 qf[2];
    #pragma unroll
    for (int kc = 0; kc < 2; kc++)
        qf[kc] = *(const f16x8*)&Qs[wave * 16 + ln][kc * 32 + quad * 8];

    float m_i[4], l_i[4];
    #pragma unroll
    for (int r = 0; r < 4; r++) { m_i[r] = -3e30f; l_i[r] = 0.f; }
    f32x4 o[4] = {};

    for (int kt = 0; kt <= qt; kt++) {
        __syncthreads();   // protect Ks/Vs from previous iteration's readers
        #pragma unroll
        for (int i = 0; i < 2; i++) {
            int vi = tid + i * 256;
            int row = vi >> 3, kk = (vi & 7) * 8;
            *(uint4*)&Ks[row][kk] = *(const uint4*)&Kh[(size_t)(kt * 64 + row) * 64 + kk];
            *(uint4*)&Vs[row][kk] = *(const uint4*)&Vh[(size_t)row * 2048 + kt * 64 + kk];
        }
        __syncthreads();

        // S = Q K^T : wave's 16 rows x 64 keys
        f32x4 sf[4] = {};
        #pragma unroll
        for (int kc = 0; kc < 2; kc++)
            #pragma unroll
            for (int ct = 0; ct < 4; ct++) {
                f16x8 kf = *(const f16x8*)&Ks[ct * 16 + ln][kc * 32 + quad * 8];
                sf[ct] = __builtin_amdgcn_mfma_f32_16x16x32_f16(qf[kc], kf, sf[ct], 0, 0, 0);
            }

        if (kt == qt) {   // diagonal tile: causal mask
            #pragma unroll
            for (int ct = 0; ct < 4; ct++) {
                int jg = ct * 16 + ln;
                #pragma unroll
                for (int r = 0; r < 4; r++) {
                    int ig = wave * 16 + quad * 4 + r;
                    if (jg > ig) sf[ct][r] = -3e30f;
                }
            }
        }

        // online softmax over 4 rows (row = 16 lanes x 4 regs)
        float alpha[4];
        #pragma unroll
        for (int r = 0; r < 4; r++) {
            float tm = fmaxf(fmaxf(sf[0][r], sf[1][r]), fmaxf(sf[2][r], sf[3][r]));
            #pragma unroll
            for (int off = 1; off < 16; off <<= 1) tm = fmaxf(tm, __shfl_xor(tm, off, 64));
            float mnew = fmaxf(m_i[r], tm);
            float a = __expf(m_i[r] - mnew);
            float rs = 0.f;
            #pragma unroll
            for (int ct = 0; ct < 4; ct++) {
                float p = __expf(sf[ct][r] - mnew);
                sf[ct][r] = p; rs += p;
            }
            #pragma unroll
            for (int off = 1; off < 16; off <<= 1) rs += __shfl_xor(rs, off, 64);
            m_i[r] = mnew; l_i[r] = l_i[r] * a + rs; alpha[r] = a;
        }
        #pragma unroll
        for (int vt = 0; vt < 4; vt++)
            #pragma unroll
            for (int r = 0; r < 4; r++) o[vt][r] *= alpha[r];

        // P: C-layout -> per-wave-private LDS -> A-layout (no barrier needed)
        #pragma unroll
        for (int ct = 0; ct < 4; ct++)
            #pragma unroll
            for (int r = 0; r < 4; r++)
                Ps[wave][quad * 4 + r][ct * 16 + ln] = (f16)sf[ct][r];

        // O += P V   (A = P[q][key], B = V^T[d2][key])
        #pragma unroll
        for (int kc = 0; kc < 2; kc++) {
            f16x8 pa = *(const f16x8*)&Ps[wave][ln][kc * 32 + quad * 8];
            #pragma unroll
            for (int vt = 0; vt < 4; vt++) {
                f16x8 vb = *(const f16x8*)&Vs[vt * 16 + ln][kc * 32 + quad * 8];
                o[vt] = __builtin_amdgcn_mfma_f32_16x16x32_f16(pa, vb, o[vt], 0, 0, 0);
            }
        }
    }

    // epilogue: normalize, scatter to att[(b,s2, h*64+d2)]
    #pragma unroll
    for (int r = 0; r < 4; r++) {
        float inv = 1.0f / l_i[r];
        int s2 = qt * 64 + wave * 16 + quad * 4 + r;
        #pragma unroll
        for (int vt = 0; vt < 4; vt++) {
            int d2 = vt * 16 + ln;
            att[((size_t)b * NS + s2) * NDM + h * 64 + d2] = (f16)(o[vt][r] * inv);
        }
    }
}

extern "C" void kernel_launch(void* const* d_in, const int* in_sizes, int n_in,
                              void* d_out, int out_size, void* d_ws, size_t ws_size,
                              hipStream_t stream)
{
    const float* q  = (const float*)d_in[0];
    const float* k  = (const float*)d_in[1];
    const float* v  = (const float*)d_in[2];
    const float* Wq = (const float*)d_in[3];
    const float* Wk = (const float*)d_in[4];
    const float* Wv = (const float*)d_in[5];
    const float* Wp = (const float*)d_in[6];
    float* out = (float*)d_out;

    // workspace layout (64 MB total)
    char* ws = (char*)d_ws;
    const size_t MB = 1024 * 1024;
    f16* qb   = (f16*)(ws + 0 * MB);    // 8 MB each
    f16* kb   = (f16*)(ws + 8 * MB);
    f16* vb   = (f16*)(ws + 16 * MB);   // reused as Vt_g after gemm3 consumes it
    f16* Wqt  = (f16*)(ws + 24 * MB);   // 2 MB each
    f16* Wkt  = (f16*)(ws + 26 * MB);
    f16* Wvt  = (f16*)(ws + 28 * MB);
    f16* Wpt  = (f16*)(ws + 30 * MB);
    f16* Qp   = (f16*)(ws + 32 * MB);   // projections, (4096,1024) f16
    f16* Kp   = (f16*)(ws + 40 * MB);
    f16* Vp   = (f16*)(ws + 48 * MB);
    f16* attb = (f16*)(ws + 56 * MB);
    f16* Vtg  = vb;                     // (2,16,64,2048) transposed V heads

    const int M = NB * NS;      // 4096
    const int N = NDM;          // 1024
    const int K = NDM;          // 1024

    cast3_kernel<<<dim3(2048, 1, 3), 256, 0, stream>>>(q, k, v, qb, kb, vb, (M * NDM) / 8);
    tcast4_kernel<<<dim3(32, 32, 4), dim3(32, 8), 0, stream>>>(Wq, Wk, Wv, Wp, Wqt, Wkt, Wvt, Wpt);
    gemm3_kernel<<<dim3(N / 128, M / 128, 3), 256, 0, stream>>>(qb, kb, vb, Wqt, Wkt, Wvt, Qp, Kp, Vp, M, N, K);
    vtrans_kernel<<<dim3(32, NHEAD, NB), 256, 0, stream>>>(Vp, Vtg);
    attn_kernel<<<dim3(NS / 64, NHEAD, NB), 256, 0, stream>>>(Qp, Kp, Vtg, attb);
    gemm_out_kernel<<<dim3(N / 128, M / 128, 1), 256, 0, stream>>>(attb, Wpt, out, M, N, K);
}

// Round 3
// 241.837 us; speedup vs baseline: 1.4109x; 1.2445x over previous
//
#include <hip/hip_runtime.h>
#include <cstdint>
#include <cstddef>

// MultiHeadAttention: B=2,S=2048,D_MODEL=1024,N_HEAD=16, "buggy" reshape:
// head h of batch b is the contiguous block X[b, h*128:(h+1)*128, :] viewed (2048,64).
// R2: global_load_lds(16B) staging with XOR-swizzled global chunk fetch (LDS dest is
// wave-uniform+lane*16 -> can't pad; swizzle makes frag reads 2-lanes/bank = free),
// attn rebalanced: paired q-tiles (p,31-p) -> all 512 blocks do 17 BK=128 iters.

typedef _Float16 f16;
typedef _Float16 f16x8 __attribute__((ext_vector_type(8)));
typedef float f32x4 __attribute__((ext_vector_type(4)));

#define NB 2
#define NS 2048
#define NDM 1024
#define NHEAD 16

// async global->LDS, 16B per lane; LDS dest = wave-uniform base + lane*16
__device__ __forceinline__ void gload16(void* lds, const void* g) {
    __builtin_amdgcn_global_load_lds(
        (__attribute__((address_space(1))) void*)g,
        (__attribute__((address_space(3))) void*)lds, 16, 0, 0);
}

// ---------------- cast fp32 -> fp16 (q,k,v) ----------------
__global__ __launch_bounds__(256) void cast3_kernel(
    const float* __restrict__ s0, const float* __restrict__ s1, const float* __restrict__ s2,
    f16* __restrict__ d0, f16* __restrict__ d1, f16* __restrict__ d2, int nvec)
{
    const float* s = blockIdx.z == 0 ? s0 : (blockIdx.z == 1 ? s1 : s2);
    f16* d        = blockIdx.z == 0 ? d0 : (blockIdx.z == 1 ? d1 : d2);
    int vi = blockIdx.x * 256 + threadIdx.x;
    if (vi >= nvec) return;
    const float4* sp = (const float4*)s;
    float4 a = sp[vi * 2 + 0];
    float4 b = sp[vi * 2 + 1];
    f16x8 h;
    h[0] = (f16)a.x; h[1] = (f16)a.y; h[2] = (f16)a.z; h[3] = (f16)a.w;
    h[4] = (f16)b.x; h[5] = (f16)b.y; h[6] = (f16)b.z; h[7] = (f16)b.w;
    *(f16x8*)(d + (size_t)vi * 8) = h;
}

// ---------------- transpose + cast the 1024x1024 weight mats ----------------
__global__ __launch_bounds__(256) void tcast4_kernel(
    const float* __restrict__ w0, const float* __restrict__ w1,
    const float* __restrict__ w2, const float* __restrict__ w3,
    f16* __restrict__ t0, f16* __restrict__ t1, f16* __restrict__ t2, f16* __restrict__ t3)
{
    const int n = 1024;
    const float* W; f16* T;
    switch (blockIdx.z) {
        case 0: W = w0; T = t0; break;
        case 1: W = w1; T = t1; break;
        case 2: W = w2; T = t2; break;
        default: W = w3; T = t3; break;
    }
    __shared__ float tile[32][33];
    int tx = threadIdx.x, ty = threadIdx.y;     // block (32,8)
    int c0 = blockIdx.x * 32, r0 = blockIdx.y * 32;
    #pragma unroll
    for (int i = 0; i < 32; i += 8)
        tile[ty + i][tx] = W[(size_t)(r0 + ty + i) * n + c0 + tx];
    __syncthreads();
    #pragma unroll
    for (int i = 0; i < 32; i += 8)
        T[(size_t)(c0 + ty + i) * n + r0 + tx] = (f16)tile[tx][ty + i];
}

// ---------------- GEMM  C(MxN) = A(MxK) * Bt(NxK)^T, 128x128 tile, BK=64 ----------------
// global_load_lds staging, XOR-swizzled chunks: LDS[row][c*8] holds global chunk c^(row&7).
// Frag read for global chunk g of row r: LDS[r][(g^(r&7))*8] -> banks 2-way (free).
template <typename CT>
__device__ __forceinline__ void gemm_abt_body(
    const f16* __restrict__ A, const f16* __restrict__ Bt, CT* __restrict__ C,
    int M, int N, int K, int bx, int by)
{
    __shared__ f16 As[128][64];
    __shared__ f16 Bs[128][64];
    const int tid  = threadIdx.x;
    const int lane = tid & 63, wave = tid >> 6;
    const int quad = lane >> 4, ln = lane & 15;
    const int wm = wave >> 1, wn = wave & 1;
    const int m0 = by * 128, n0 = bx * 128;
    const int r8 = lane >> 3, c8 = lane & 7;
    const int swz = ((c8 ^ r8) * 8);           // global chunk this lane fetches

    f32x4 acc[4][4] = {};
    for (int k0 = 0; k0 < K; k0 += 64) {
        __syncthreads();
        #pragma unroll
        for (int i = 0; i < 4; i++) {
            int blk = wave * 4 + i;            // 8-row group, 0..15
            int row = blk * 8 + r8;
            gload16(&As[blk * 8][0], &A [(size_t)(m0 + row) * K + k0 + swz]);
            gload16(&Bs[blk * 8][0], &Bt[(size_t)(n0 + row) * K + k0 + swz]);
        }
        __syncthreads();
        #pragma unroll
        for (int kc = 0; kc < 2; kc++) {
            f16x8 af[4], bfr[4];
            #pragma unroll
            for (int mt = 0; mt < 4; mt++)
                af[mt] = *(const f16x8*)&As[wm * 64 + mt * 16 + ln][((kc * 4 + quad) ^ (ln & 7)) * 8];
            #pragma unroll
            for (int nt = 0; nt < 4; nt++)
                bfr[nt] = *(const f16x8*)&Bs[wn * 64 + nt * 16 + ln][((kc * 4 + quad) ^ (ln & 7)) * 8];
            #pragma unroll
            for (int mt = 0; mt < 4; mt++)
                #pragma unroll
                for (int nt = 0; nt < 4; nt++)
                    acc[mt][nt] = __builtin_amdgcn_mfma_f32_16x16x32_f16(af[mt], bfr[nt], acc[mt][nt], 0, 0, 0);
        }
    }
    #pragma unroll
    for (int mt = 0; mt < 4; mt++)
        #pragma unroll
        for (int nt = 0; nt < 4; nt++)
            #pragma unroll
            for (int r = 0; r < 4; r++) {
                int row = m0 + wm * 64 + mt * 16 + quad * 4 + r;
                int col = n0 + wn * 64 + nt * 16 + ln;
                C[(size_t)row * N + col] = (CT)acc[mt][nt][r];
            }
}

__global__ __launch_bounds__(256) void gemm3_kernel(
    const f16* __restrict__ a0, const f16* __restrict__ a1, const f16* __restrict__ a2,
    const f16* __restrict__ b0, const f16* __restrict__ b1, const f16* __restrict__ b2,
    f16* __restrict__ c0, f16* __restrict__ c1, f16* __restrict__ c2, int M, int N, int K)
{
    const f16 *A, *Bt; f16* C;
    switch (blockIdx.z) {
        case 0: A = a0; Bt = b0; C = c0; break;
        case 1: A = a1; Bt = b1; C = c1; break;
        default: A = a2; Bt = b2; C = c2; break;
    }
    gemm_abt_body<f16>(A, Bt, C, M, N, K, blockIdx.x, blockIdx.y);
}

__global__ __launch_bounds__(256) void gemm_out_kernel(
    const f16* __restrict__ A, const f16* __restrict__ Bt, float* __restrict__ C, int M, int N, int K)
{
    gemm_abt_body<float>(A, Bt, C, M, N, K, blockIdx.x, blockIdx.y);
}

// ---------------- global V transpose: per head (2048x64) -> (64x2048) ----------------
__global__ __launch_bounds__(256) void vtrans_kernel(
    const f16* __restrict__ Vp, f16* __restrict__ Vt)
{
    const int kt = blockIdx.x;   // key tile of 64
    const int h  = blockIdx.y;
    const int b  = blockIdx.z;
    const f16* src = Vp + (size_t)b * (NS * NDM) + (size_t)h * (128 * NDM);  // (2048,64)
    f16* dst = Vt + (size_t)(b * NHEAD + h) * (64 * 2048);

    __shared__ f16 Ls[64][64];
    const int tid = threadIdx.x;
    #pragma unroll
    for (int i = 0; i < 2; i++) {
        int vi = tid + i * 256;
        int key = vi >> 3, c = vi & 7;
        int cs = c ^ ((key >> 3) & 7);
        *(uint4*)&Ls[key][cs * 8] = *(const uint4*)&src[(size_t)(kt * 64 + key) * 64 + c * 8];
    }
    __syncthreads();
    #pragma unroll
    for (int i = 0; i < 2; i++) {
        int vi = tid + i * 256;
        int d2 = vi >> 3, kc = vi & 7;
        int cs = (d2 >> 3) ^ kc;
        f16 tmp[8];
        #pragma unroll
        for (int j = 0; j < 8; j++)
            tmp[j] = Ls[kc * 8 + j][cs * 8 + (d2 & 7)];
        *(uint4*)&dst[(size_t)d2 * 2048 + kt * 64 + kc * 8] = *(uint4*)tmp;
    }
}

// ---------------- flash attention v3 ----------------
// Block p handles q-tiles (31-p) then (p): exactly 17 BK=128 iterations each ->
// perfectly balanced 512-block grid. K/V staged via global_load_lds w/ XOR swizzle.
__global__ __launch_bounds__(256) void attn_kernel(
    const f16* __restrict__ Qp, const f16* __restrict__ Kp, const f16* __restrict__ Vt,
    f16* __restrict__ att)
{
    const int p = blockIdx.x;    // 0..15 pair index
    const int h = blockIdx.y;
    const int b = blockIdx.z;
    const size_t hb = (size_t)b * (NS * NDM) + (size_t)h * (128 * NDM);
    const f16* Qh = Qp + hb;                                    // (2048,64)
    const f16* Kh = Kp + hb;                                    // (2048,64)
    const f16* Vh = Vt + (size_t)(b * NHEAD + h) * (64 * 2048); // (64,2048) transposed

    __shared__ f16 Qs[64][72];       //  9.0 KB (padded; plain staging)
    __shared__ f16 Ks[128][64];      // 16.0 KB (swizzle row&7)
    __shared__ f16 Vs[64][128];      // 16.0 KB Vs[d2][key] (swizzle row&15)
    __shared__ f16 Ps[4][16][132];   // 16.5 KB per-wave-private P

    const int tid  = threadIdx.x;
    const int lane = tid & 63, wave = tid >> 6;
    const int quad = lane >> 4, ln = lane & 15;
    const int r8 = lane >> 3, c8 = lane & 7;      // K staging coords
    const int r4 = lane >> 4, c16 = lane & 15;    // V staging coords

    for (int pass = 0; pass < 2; pass++) {
        const int qt = pass == 0 ? (31 - p) : p;
        __syncthreads();   // previous pass readers of Qs/Ks/Vs done
        // stage Q tile (plain, padded)
        #pragma unroll
        for (int i = 0; i < 2; i++) {
            int vi = tid + i * 256;
            int row = vi >> 3, kk = (vi & 7) * 8;
            *(uint4*)&Qs[row][kk] = *(const uint4*)&Qh[(size_t)(qt * 64 + row) * 64 + kk];
        }
        __syncthreads();
        f16x8 qf[2];
        #pragma unroll
        for (int kc = 0; kc < 2; kc++)
            qf[kc] = *(const f16x8*)&Qs[wave * 16 + ln][kc * 32 + quad * 8];

        float m_i[4], l_i[4];
        #pragma unroll
        for (int r = 0; r < 4; r++) { m_i[r] = -3e30f; l_i[r] = 0.f; }
        f32x4 o[4] = {};

        const int nkt = (qt + 2) >> 1;    // BK=128 tiles covering (qt+1)*64 keys
        for (int kt = 0; kt < nkt; kt++) {
            __syncthreads();   // previous iteration's Ks/Vs readers done
            #pragma unroll
            for (int i = 0; i < 4; i++) {
                int blk = wave * 4 + i;                 // 0..15
                int krow = blk * 8 + r8;                // 0..127
                gload16(&Ks[blk * 8][0], &Kh[(size_t)(kt * 128 + krow) * 64 + ((c8 ^ r8) * 8)]);
                int vrow = blk * 4 + r4;                // 0..63
                gload16(&Vs[blk * 4][0], &Vh[(size_t)vrow * 2048 + kt * 128 + ((c16 ^ (vrow & 15)) * 8)]);
            }
            __syncthreads();

            // S = Q K^T : wave's 16 rows x 128 keys
            f32x4 sf[8] = {};
            #pragma unroll
            for (int kc = 0; kc < 2; kc++)
                #pragma unroll
                for (int ct = 0; ct < 8; ct++) {
                    int krow = ct * 16 + ln;
                    f16x8 kf = *(const f16x8*)&Ks[krow][((kc * 4 + quad) ^ (ln & 7)) * 8];
                    sf[ct] = __builtin_amdgcn_mfma_f32_16x16x32_f16(qf[kc], kf, sf[ct], 0, 0, 0);
                }

            if (kt == nkt - 1) {   // diagonal tile: causal mask (also kills tail over-span)
                #pragma unroll
                for (int ct = 0; ct < 8; ct++) {
                    int jg = kt * 128 + ct * 16 + ln;
                    #pragma unroll
                    for (int r = 0; r < 4; r++) {
                        int ig = qt * 64 + wave * 16 + quad * 4 + r;
                        if (jg > ig) sf[ct][r] = -3e30f;
                    }
                }
            }

            // online softmax: 4 rows, each spread over 16 lanes x 8 regs
            float alpha[4];
            #pragma unroll
            for (int r = 0; r < 4; r++) {
                float tm = sf[0][r];
                #pragma unroll
                for (int ct = 1; ct < 8; ct++) tm = fmaxf(tm, sf[ct][r]);
                #pragma unroll
                for (int off = 1; off < 16; off <<= 1) tm = fmaxf(tm, __shfl_xor(tm, off, 64));
                float mnew = fmaxf(m_i[r], tm);
                float a = __expf(m_i[r] - mnew);
                float rs = 0.f;
                #pragma unroll
                for (int ct = 0; ct < 8; ct++) {
                    float pv = __expf(sf[ct][r] - mnew);
                    sf[ct][r] = pv; rs += pv;
                }
                #pragma unroll
                for (int off = 1; off < 16; off <<= 1) rs += __shfl_xor(rs, off, 64);
                m_i[r] = mnew; l_i[r] = l_i[r] * a + rs; alpha[r] = a;
            }
            #pragma unroll
            for (int vt = 0; vt < 4; vt++)
                #pragma unroll
                for (int r = 0; r < 4; r++) o[vt][r] *= alpha[r];

            // P: C-layout -> per-wave-private LDS -> A-layout (no barrier)
            #pragma unroll
            for (int ct = 0; ct < 8; ct++)
                #pragma unroll
                for (int r = 0; r < 4; r++)
                    Ps[wave][quad * 4 + r][ct * 16 + ln] = (f16)sf[ct][r];

            // O += P V  (A = P[q][key] 16x128, B = V^T[d2][key])
            #pragma unroll
            for (int kc = 0; kc < 4; kc++) {
                f16x8 pa = *(const f16x8*)&Ps[wave][ln][kc * 32 + quad * 8];
                #pragma unroll
                for (int vt = 0; vt < 4; vt++) {
                    int vrow = vt * 16 + ln;
                    f16x8 vb = *(const f16x8*)&Vs[vrow][(((kc * 4 + quad) ^ ln) & 15) * 8];
                    o[vt] = __builtin_amdgcn_mfma_f32_16x16x32_f16(pa, vb, o[vt], 0, 0, 0);
                }
            }
        }

        // epilogue: normalize, scatter to att[(b,s2, h*64+d2)]
        #pragma unroll
        for (int r = 0; r < 4; r++) {
            float inv = 1.0f / l_i[r];
            int s2 = qt * 64 + wave * 16 + quad * 4 + r;
            #pragma unroll
            for (int vt = 0; vt < 4; vt++) {
                int d2 = vt * 16 + ln;
                att[((size_t)b * NS + s2) * NDM + h * 64 + d2] = (f16)(o[vt][r] * inv);
            }
        }
    }
}

extern "C" void kernel_launch(void* const* d_in, const int* in_sizes, int n_in,
                              void* d_out, int out_size, void* d_ws, size_t ws_size,
                              hipStream_t stream)
{
    const float* q  = (const float*)d_in[0];
    const float* k  = (const float*)d_in[1];
    const float* v  = (const float*)d_in[2];
    const float* Wq = (const float*)d_in[3];
    const float* Wk = (const float*)d_in[4];
    const float* Wv = (const float*)d_in[5];
    const float* Wp = (const float*)d_in[6];
    float* out = (float*)d_out;

    char* ws = (char*)d_ws;
    const size_t MB = 1024 * 1024;
    f16* qb   = (f16*)(ws + 0 * MB);
    f16* kb   = (f16*)(ws + 8 * MB);
    f16* vb   = (f16*)(ws + 16 * MB);   // reused as Vtg after gemm3 consumes it
    f16* Wqt  = (f16*)(ws + 24 * MB);
    f16* Wkt  = (f16*)(ws + 26 * MB);
    f16* Wvt  = (f16*)(ws + 28 * MB);
    f16* Wpt  = (f16*)(ws + 30 * MB);
    f16* Qp   = (f16*)(ws + 32 * MB);
    f16* Kp   = (f16*)(ws + 40 * MB);
    f16* Vp   = (f16*)(ws + 48 * MB);
    f16* attb = (f16*)(ws + 56 * MB);
    f16* Vtg  = vb;                     // (2,16,64,2048) transposed V heads

    const int M = NB * NS;      // 4096
    const int N = NDM;          // 1024
    const int K = NDM;          // 1024

    cast3_kernel<<<dim3(2048, 1, 3), 256, 0, stream>>>(q, k, v, qb, kb, vb, (M * NDM) / 8);
    tcast4_kernel<<<dim3(32, 32, 4), dim3(32, 8), 0, stream>>>(Wq, Wk, Wv, Wp, Wqt, Wkt, Wvt, Wpt);
    gemm3_kernel<<<dim3(N / 128, M / 128, 3), 256, 0, stream>>>(qb, kb, vb, Wqt, Wkt, Wvt, Qp, Kp, Vp, M, N, K);
    vtrans_kernel<<<dim3(32, NHEAD, NB), 256, 0, stream>>>(Vp, Vtg);
    attn_kernel<<<dim3(16, NHEAD, NB), 256, 0, stream>>>(Qp, Kp, Vtg, attb);
    gemm_out_kernel<<<dim3(N / 128, M / 128, 1), 256, 0, stream>>>(attb, Wpt, out, M, N, K);
}

// Round 4
// 235.378 us; speedup vs baseline: 1.4496x; 1.0274x over previous
//
#include <hip/hip_runtime.h>
#include <cstdint>
#include <cstddef>

// MultiHeadAttention: B=2,S=2048,D_MODEL=1024,N_HEAD=16, "buggy" reshape:
// head h of batch b is the contiguous block X[b, h*128:(h+1)*128, :] viewed (2048,64).
// R4: attn LDS 57.5->49KB (P overlaid on dead Q tile) -> 3 blocks/CU; softmax in
// exp2 domain (log2e folded into the Q projection epilogue -> bare v_exp_f32).

typedef _Float16 f16;
typedef _Float16 f16x8 __attribute__((ext_vector_type(8)));
typedef float f32x4 __attribute__((ext_vector_type(4)));

#define NB 2
#define NS 2048
#define NDM 1024
#define NHEAD 16

// async global->LDS, 16B per lane; LDS dest = wave-uniform base + lane*16
__device__ __forceinline__ void gload16(void* lds, const void* g) {
    __builtin_amdgcn_global_load_lds(
        (__attribute__((address_space(1))) void*)g,
        (__attribute__((address_space(3))) void*)lds, 16, 0, 0);
}

__device__ __forceinline__ float fast_exp2(float x) {
#if __has_builtin(__builtin_amdgcn_exp2f)
    return __builtin_amdgcn_exp2f(x);
#else
    return __expf(x * 0.69314718055994531f);
#endif
}

// ---------------- cast fp32 -> fp16 (q,k,v) ----------------
__global__ __launch_bounds__(256) void cast3_kernel(
    const float* __restrict__ s0, const float* __restrict__ s1, const float* __restrict__ s2,
    f16* __restrict__ d0, f16* __restrict__ d1, f16* __restrict__ d2, int nvec)
{
    const float* s = blockIdx.z == 0 ? s0 : (blockIdx.z == 1 ? s1 : s2);
    f16* d        = blockIdx.z == 0 ? d0 : (blockIdx.z == 1 ? d1 : d2);
    int vi = blockIdx.x * 256 + threadIdx.x;
    if (vi >= nvec) return;
    const float4* sp = (const float4*)s;
    float4 a = sp[vi * 2 + 0];
    float4 b = sp[vi * 2 + 1];
    f16x8 h;
    h[0] = (f16)a.x; h[1] = (f16)a.y; h[2] = (f16)a.z; h[3] = (f16)a.w;
    h[4] = (f16)b.x; h[5] = (f16)b.y; h[6] = (f16)b.z; h[7] = (f16)b.w;
    *(f16x8*)(d + (size_t)vi * 8) = h;
}

// ---------------- transpose + cast the 1024x1024 weight mats ----------------
__global__ __launch_bounds__(256) void tcast4_kernel(
    const float* __restrict__ w0, const float* __restrict__ w1,
    const float* __restrict__ w2, const float* __restrict__ w3,
    f16* __restrict__ t0, f16* __restrict__ t1, f16* __restrict__ t2, f16* __restrict__ t3)
{
    const int n = 1024;
    const float* W; f16* T;
    switch (blockIdx.z) {
        case 0: W = w0; T = t0; break;
        case 1: W = w1; T = t1; break;
        case 2: W = w2; T = t2; break;
        default: W = w3; T = t3; break;
    }
    __shared__ float tile[32][33];
    int tx = threadIdx.x, ty = threadIdx.y;     // block (32,8)
    int c0 = blockIdx.x * 32, r0 = blockIdx.y * 32;
    #pragma unroll
    for (int i = 0; i < 32; i += 8)
        tile[ty + i][tx] = W[(size_t)(r0 + ty + i) * n + c0 + tx];
    __syncthreads();
    #pragma unroll
    for (int i = 0; i < 32; i += 8)
        T[(size_t)(c0 + ty + i) * n + r0 + tx] = (f16)tile[tx][ty + i];
}

// ---------------- GEMM  C(MxN) = A(MxK) * Bt(NxK)^T, 128x128 tile, BK=64 ----------------
// global_load_lds staging, XOR-swizzled chunks: LDS[row][c*8] holds global chunk c^(row&7).
// Frag read for global chunk g of row r: LDS[r][(g^(r&7))*8] -> banks 2-way (free).
template <typename CT>
__device__ __forceinline__ void gemm_abt_body(
    const f16* __restrict__ A, const f16* __restrict__ Bt, CT* __restrict__ C,
    int M, int N, int K, int bx, int by, float cscale)
{
    __shared__ f16 As[128][64];
    __shared__ f16 Bs[128][64];
    const int tid  = threadIdx.x;
    const int lane = tid & 63, wave = tid >> 6;
    const int quad = lane >> 4, ln = lane & 15;
    const int wm = wave >> 1, wn = wave & 1;
    const int m0 = by * 128, n0 = bx * 128;
    const int r8 = lane >> 3, c8 = lane & 7;
    const int swz = ((c8 ^ r8) * 8);           // global chunk this lane fetches

    f32x4 acc[4][4] = {};
    for (int k0 = 0; k0 < K; k0 += 64) {
        __syncthreads();
        #pragma unroll
        for (int i = 0; i < 4; i++) {
            int blk = wave * 4 + i;            // 8-row group, 0..15
            int row = blk * 8 + r8;
            gload16(&As[blk * 8][0], &A [(size_t)(m0 + row) * K + k0 + swz]);
            gload16(&Bs[blk * 8][0], &Bt[(size_t)(n0 + row) * K + k0 + swz]);
        }
        __syncthreads();
        #pragma unroll
        for (int kc = 0; kc < 2; kc++) {
            f16x8 af[4], bfr[4];
            #pragma unroll
            for (int mt = 0; mt < 4; mt++)
                af[mt] = *(const f16x8*)&As[wm * 64 + mt * 16 + ln][((kc * 4 + quad) ^ (ln & 7)) * 8];
            #pragma unroll
            for (int nt = 0; nt < 4; nt++)
                bfr[nt] = *(const f16x8*)&Bs[wn * 64 + nt * 16 + ln][((kc * 4 + quad) ^ (ln & 7)) * 8];
            #pragma unroll
            for (int mt = 0; mt < 4; mt++)
                #pragma unroll
                for (int nt = 0; nt < 4; nt++)
                    acc[mt][nt] = __builtin_amdgcn_mfma_f32_16x16x32_f16(af[mt], bfr[nt], acc[mt][nt], 0, 0, 0);
        }
    }
    #pragma unroll
    for (int mt = 0; mt < 4; mt++)
        #pragma unroll
        for (int nt = 0; nt < 4; nt++)
            #pragma unroll
            for (int r = 0; r < 4; r++) {
                int row = m0 + wm * 64 + mt * 16 + quad * 4 + r;
                int col = n0 + wn * 64 + nt * 16 + ln;
                C[(size_t)row * N + col] = (CT)(acc[mt][nt][r] * cscale);
            }
}

__global__ __launch_bounds__(256) void gemm3_kernel(
    const f16* __restrict__ a0, const f16* __restrict__ a1, const f16* __restrict__ a2,
    const f16* __restrict__ b0, const f16* __restrict__ b1, const f16* __restrict__ b2,
    f16* __restrict__ c0, f16* __restrict__ c1, f16* __restrict__ c2, int M, int N, int K)
{
    const f16 *A, *Bt; f16* C; float sc;
    switch (blockIdx.z) {
        case 0: A = a0; Bt = b0; C = c0; sc = 1.4426950408889634f; break;  // Q * log2(e)
        case 1: A = a1; Bt = b1; C = c1; sc = 1.0f; break;
        default: A = a2; Bt = b2; C = c2; sc = 1.0f; break;
    }
    gemm_abt_body<f16>(A, Bt, C, M, N, K, blockIdx.x, blockIdx.y, sc);
}

__global__ __launch_bounds__(256) void gemm_out_kernel(
    const f16* __restrict__ A, const f16* __restrict__ Bt, float* __restrict__ C, int M, int N, int K)
{
    gemm_abt_body<float>(A, Bt, C, M, N, K, blockIdx.x, blockIdx.y, 1.0f);
}

// ---------------- global V transpose: per head (2048x64) -> (64x2048) ----------------
__global__ __launch_bounds__(256) void vtrans_kernel(
    const f16* __restrict__ Vp, f16* __restrict__ Vt)
{
    const int kt = blockIdx.x;   // key tile of 64
    const int h  = blockIdx.y;
    const int b  = blockIdx.z;
    const f16* src = Vp + (size_t)b * (NS * NDM) + (size_t)h * (128 * NDM);  // (2048,64)
    f16* dst = Vt + (size_t)(b * NHEAD + h) * (64 * 2048);

    __shared__ f16 Ls[64][64];
    const int tid = threadIdx.x;
    #pragma unroll
    for (int i = 0; i < 2; i++) {
        int vi = tid + i * 256;
        int key = vi >> 3, c = vi & 7;
        int cs = c ^ ((key >> 3) & 7);
        *(uint4*)&Ls[key][cs * 8] = *(const uint4*)&src[(size_t)(kt * 64 + key) * 64 + c * 8];
    }
    __syncthreads();
    #pragma unroll
    for (int i = 0; i < 2; i++) {
        int vi = tid + i * 256;
        int d2 = vi >> 3, kc = vi & 7;
        int cs = (d2 >> 3) ^ kc;
        f16 tmp[8];
        #pragma unroll
        for (int j = 0; j < 8; j++)
            tmp[j] = Ls[kc * 8 + j][cs * 8 + (d2 & 7)];
        *(uint4*)&dst[(size_t)d2 * 2048 + kt * 64 + kc * 8] = *(uint4*)tmp;
    }
}

// ---------------- flash attention v4 ----------------
// Block p handles q-tiles (31-p) then (p): exactly 17 BK=128 iterations each.
// LDS 49KB (P overlaid on dead Q tile) -> 3 blocks/CU. Softmax in exp2 domain
// (Q projection pre-scaled by log2e).
__global__ __launch_bounds__(256) void attn_kernel(
    const f16* __restrict__ Qp, const f16* __restrict__ Kp, const f16* __restrict__ Vt,
    f16* __restrict__ att)
{
    const int p = blockIdx.x;    // 0..15 pair index
    const int h = blockIdx.y;
    const int b = blockIdx.z;
    const size_t hb = (size_t)b * (NS * NDM) + (size_t)h * (128 * NDM);
    const f16* Qh = Qp + hb;                                    // (2048,64), pre-scaled log2e
    const f16* Kh = Kp + hb;                                    // (2048,64)
    const f16* Vh = Vt + (size_t)(b * NHEAD + h) * (64 * 2048); // (64,2048) transposed

    __shared__ f16 PQ[64][136];      // 17 KB union: Q tile (cols 0..63) -> per-wave P
    __shared__ f16 Ks[128][64];      // 16 KB (XOR swizzle row&7)
    __shared__ f16 Vs[64][128];      // 16 KB Vs[d2][key] (XOR swizzle row&15)

    const int tid  = threadIdx.x;
    const int lane = tid & 63, wave = tid >> 6;
    const int quad = lane >> 4, ln = lane & 15;
    const int r8 = lane >> 3, c8 = lane & 7;      // K staging coords
    const int r4 = lane >> 4, c16 = lane & 15;    // V staging coords

    for (int pass = 0; pass < 2; pass++) {
        const int qt = pass == 0 ? (31 - p) : p;
        __syncthreads();   // previous pass readers of PQ/Ks/Vs done
        // stage Q tile into the union buffer (plain vector stores)
        #pragma unroll
        for (int i = 0; i < 2; i++) {
            int vi = tid + i * 256;
            int row = vi >> 3, kk = (vi & 7) * 8;
            *(uint4*)&PQ[row][kk] = *(const uint4*)&Qh[(size_t)(qt * 64 + row) * 64 + kk];
        }
        __syncthreads();
        f16x8 qf[2];
        #pragma unroll
        for (int kc = 0; kc < 2; kc++)
            qf[kc] = *(const f16x8*)&PQ[wave * 16 + ln][kc * 32 + quad * 8];

        float m_i[4], l_i[4];
        #pragma unroll
        for (int r = 0; r < 4; r++) { m_i[r] = -3e30f; l_i[r] = 0.f; }
        f32x4 o[4] = {};

        const int nkt = (qt + 2) >> 1;    // BK=128 tiles covering (qt+1)*64 keys
        for (int kt = 0; kt < nkt; kt++) {
            __syncthreads();   // previous iteration's Ks/Vs readers done (also guards PQ->P flip)
            #pragma unroll
            for (int i = 0; i < 4; i++) {
                int blk = wave * 4 + i;                 // 0..15
                int krow = blk * 8 + r8;                // 0..127
                gload16(&Ks[blk * 8][0], &Kh[(size_t)(kt * 128 + krow) * 64 + ((c8 ^ r8) * 8)]);
                int vrow = blk * 4 + r4;                // 0..63
                gload16(&Vs[blk * 4][0], &Vh[(size_t)vrow * 2048 + kt * 128 + ((c16 ^ (vrow & 15)) * 8)]);
            }
            __syncthreads();

            // S2 = (Q*log2e) K^T : wave's 16 rows x 128 keys
            f32x4 sf[8] = {};
            #pragma unroll
            for (int kc = 0; kc < 2; kc++)
                #pragma unroll
                for (int ct = 0; ct < 8; ct++) {
                    int krow = ct * 16 + ln;
                    f16x8 kf = *(const f16x8*)&Ks[krow][((kc * 4 + quad) ^ (ln & 7)) * 8];
                    sf[ct] = __builtin_amdgcn_mfma_f32_16x16x32_f16(qf[kc], kf, sf[ct], 0, 0, 0);
                }

            if (kt == nkt - 1) {   // diagonal tile: causal mask (also kills tail over-span)
                #pragma unroll
                for (int ct = 0; ct < 8; ct++) {
                    int jg = kt * 128 + ct * 16 + ln;
                    #pragma unroll
                    for (int r = 0; r < 4; r++) {
                        int ig = qt * 64 + wave * 16 + quad * 4 + r;
                        if (jg > ig) sf[ct][r] = -3e30f;
                    }
                }
            }

            // online softmax in exp2 domain: 4 rows, each 16 lanes x 8 regs
            float alpha[4];
            #pragma unroll
            for (int r = 0; r < 4; r++) {
                float tm = sf[0][r];
                #pragma unroll
                for (int ct = 1; ct < 8; ct++) tm = fmaxf(tm, sf[ct][r]);
                #pragma unroll
                for (int off = 1; off < 16; off <<= 1) tm = fmaxf(tm, __shfl_xor(tm, off, 64));
                float mnew = fmaxf(m_i[r], tm);
                float a = fast_exp2(m_i[r] - mnew);
                float rs = 0.f;
                #pragma unroll
                for (int ct = 0; ct < 8; ct++) {
                    float pv = fast_exp2(sf[ct][r] - mnew);
                    sf[ct][r] = pv; rs += pv;
                }
                #pragma unroll
                for (int off = 1; off < 16; off <<= 1) rs += __shfl_xor(rs, off, 64);
                m_i[r] = mnew; l_i[r] = l_i[r] * a + rs; alpha[r] = a;
            }
            #pragma unroll
            for (int vt = 0; vt < 4; vt++)
                #pragma unroll
                for (int r = 0; r < 4; r++) o[vt][r] *= alpha[r];

            // P: C-layout -> per-wave-private rows of PQ -> A-layout (no barrier:
            // each wave writes/reads only rows [wave*16, wave*16+16) )
            #pragma unroll
            for (int ct = 0; ct < 8; ct++)
                #pragma unroll
                for (int r = 0; r < 4; r++)
                    PQ[wave * 16 + quad * 4 + r][ct * 16 + ln] = (f16)sf[ct][r];

            // O += P V  (A = P[q][key] 16x128, B = V^T[d2][key])
            #pragma unroll
            for (int kc = 0; kc < 4; kc++) {
                f16x8 pa = *(const f16x8*)&PQ[wave * 16 + ln][kc * 32 + quad * 8];
                #pragma unroll
                for (int vt = 0; vt < 4; vt++) {
                    int vrow = vt * 16 + ln;
                    f16x8 vb = *(const f16x8*)&Vs[vrow][(((kc * 4 + quad) ^ ln) & 15) * 8];
                    o[vt] = __builtin_amdgcn_mfma_f32_16x16x32_f16(pa, vb, o[vt], 0, 0, 0);
                }
            }
        }

        // epilogue: normalize, scatter to att[(b,s2, h*64+d2)]
        #pragma unroll
        for (int r = 0; r < 4; r++) {
            float inv = 1.0f / l_i[r];
            int s2 = qt * 64 + wave * 16 + quad * 4 + r;
            #pragma unroll
            for (int vt = 0; vt < 4; vt++) {
                int d2 = vt * 16 + ln;
                att[((size_t)b * NS + s2) * NDM + h * 64 + d2] = (f16)(o[vt][r] * inv);
            }
        }
    }
}

extern "C" void kernel_launch(void* const* d_in, const int* in_sizes, int n_in,
                              void* d_out, int out_size, void* d_ws, size_t ws_size,
                              hipStream_t stream)
{
    const float* q  = (const float*)d_in[0];
    const float* k  = (const float*)d_in[1];
    const float* v  = (const float*)d_in[2];
    const float* Wq = (const float*)d_in[3];
    const float* Wk = (const float*)d_in[4];
    const float* Wv = (const float*)d_in[5];
    const float* Wp = (const float*)d_in[6];
    float* out = (float*)d_out;

    char* ws = (char*)d_ws;
    const size_t MB = 1024 * 1024;
    f16* qb   = (f16*)(ws + 0 * MB);
    f16* kb   = (f16*)(ws + 8 * MB);
    f16* vb   = (f16*)(ws + 16 * MB);   // reused as Vtg after gemm3 consumes it
    f16* Wqt  = (f16*)(ws + 24 * MB);
    f16* Wkt  = (f16*)(ws + 26 * MB);
    f16* Wvt  = (f16*)(ws + 28 * MB);
    f16* Wpt  = (f16*)(ws + 30 * MB);
    f16* Qp   = (f16*)(ws + 32 * MB);
    f16* Kp   = (f16*)(ws + 40 * MB);
    f16* Vp   = (f16*)(ws + 48 * MB);
    f16* attb = (f16*)(ws + 56 * MB);
    f16* Vtg  = vb;                     // (2,16,64,2048) transposed V heads

    const int M = NB * NS;      // 4096
    const int N = NDM;          // 1024
    const int K = NDM;          // 1024

    cast3_kernel<<<dim3(2048, 1, 3), 256, 0, stream>>>(q, k, v, qb, kb, vb, (M * NDM) / 8);
    tcast4_kernel<<<dim3(32, 32, 4), dim3(32, 8), 0, stream>>>(Wq, Wk, Wv, Wp, Wqt, Wkt, Wvt, Wpt);
    gemm3_kernel<<<dim3(N / 128, M / 128, 3), 256, 0, stream>>>(qb, kb, vb, Wqt, Wkt, Wvt, Qp, Kp, Vp, M, N, K);
    vtrans_kernel<<<dim3(32, NHEAD, NB), 256, 0, stream>>>(Vp, Vtg);
    attn_kernel<<<dim3(16, NHEAD, NB), 256, 0, stream>>>(Qp, Kp, Vtg, attb);
    gemm_out_kernel<<<dim3(N / 128, M / 128, 1), 256, 0, stream>>>(attb, Wpt, out, M, N, K);
}